// Round 1
// baseline (1812.890 us; speedup 1.0000x reference)
//
#include <hip/hip_runtime.h>

#define DECAY 0.99f
#define OMDECAY 0.01f
#define EPSV 1e-5f

// Sizes
// z: (32, 256, 32, 32) fp32 -> 8388608 elems; tokens N = 32*32*32 = 32768, D=256, K=1024
// out layout (floats, concatenated in return order):
//   z_q_st   [0,        8388608)
//   indices  [8388608,  8421376)   (written as float values)
//   vq_loss  [8421376]  (1)
//   new_embed      [8421377, 8683521)
//   new_cluster    [8683521, 8684545)
//   new_embed_avg  [8684545, 8946689)
// ws layout (floats):
//   embedT   [0,      262144)   (256 x 1024, d-major)
//   es       [262144, 524288)
//   cs       [524288, 525312)
//   enorm    [525312, 526336)
//   csnorm   [526336, 527360)
//   loss_sum [527360]

__global__ void transpose_embed(const float* __restrict__ embed, float* __restrict__ embedT) {
    int idx = blockIdx.x * 256 + threadIdx.x;   // 0..262143
    int k = idx >> 8;
    int d = idx & 255;
    embedT[d * 1024 + k] = embed[idx];
}

__global__ void compute_enorm(const float* __restrict__ embed, float* __restrict__ enorm) {
    int wv = threadIdx.x >> 6;
    int lane = threadIdx.x & 63;
    int k = blockIdx.x * 4 + wv;                // 256 blocks * 4 waves = 1024 codes
    const float* row = embed + k * 256;
    float s = 0.f;
#pragma unroll
    for (int j = 0; j < 4; ++j) {
        float v = row[lane + 64 * j];
        s += v * v;
    }
    for (int off = 32; off > 0; off >>= 1) s += __shfl_down(s, off);
    if (lane == 0) enorm[k] = s;
}

// Main: 512 blocks x 256 threads. Each block = 64 tokens (one lane per token).
// Wave w handles codes [w*256, (w+1)*256) in 16-code chunks; B is wave-uniform.
__global__ __launch_bounds__(256, 2) void vq_main(
    const float* __restrict__ z,
    const float* __restrict__ embed,
    const float* __restrict__ embedT,
    const float* __restrict__ enorm,
    float* __restrict__ out_zq,
    float* __restrict__ out_idx,
    float* __restrict__ es,
    float* __restrict__ cs,
    float* __restrict__ loss_sum)
{
    __shared__ float As[256 * 64];   // [d][token] 64 KB
    __shared__ float smv[256];
    __shared__ int   smi[256];
    __shared__ int   sidx[64];

    const int lane = threadIdx.x & 63;
    const int wv   = threadIdx.x >> 6;
    const int t0   = blockIdx.x * 64;          // global token base
    const int b_idx = t0 >> 10;                // batch index (64 tokens share b)
    const int hw0   = t0 & 1023;
    const int zbase = b_idx * 262144 + hw0;    // + d*1024 + lane

    // Stage A tile: coalesced (64 consecutive floats per wave-row)
    for (int d = wv; d < 256; d += 4)
        As[d * 64 + lane] = z[zbase + d * 1024 + lane];
    __syncthreads();

    const int uwv = __builtin_amdgcn_readfirstlane(wv);   // wave-uniform wave id
    float bestv = 3.4e38f;
    int   besti = 0;

    for (int c = 0; c < 16; ++c) {
        const int kbase = uwv * 256 + c * 16;
        float acc[16];
#pragma unroll
        for (int j = 0; j < 16; ++j) acc[j] = 0.f;
        const float* bp = embedT + kbase;
#pragma unroll 4
        for (int d = 0; d < 256; ++d) {
            float a = As[d * 64 + lane];
            const float4 b0 = *(const float4*)(bp + d * 1024 + 0);
            const float4 b1 = *(const float4*)(bp + d * 1024 + 4);
            const float4 b2 = *(const float4*)(bp + d * 1024 + 8);
            const float4 b3 = *(const float4*)(bp + d * 1024 + 12);
            acc[0]  += a * b0.x;  acc[1]  += a * b0.y;
            acc[2]  += a * b0.z;  acc[3]  += a * b0.w;
            acc[4]  += a * b1.x;  acc[5]  += a * b1.y;
            acc[6]  += a * b1.z;  acc[7]  += a * b1.w;
            acc[8]  += a * b2.x;  acc[9]  += a * b2.y;
            acc[10] += a * b2.z;  acc[11] += a * b2.w;
            acc[12] += a * b3.x;  acc[13] += a * b3.y;
            acc[14] += a * b3.z;  acc[15] += a * b3.w;
        }
#pragma unroll
        for (int j = 0; j < 16; ++j) {
            float sc = enorm[kbase + j] - 2.0f * acc[j];
            if (sc < bestv) { bestv = sc; besti = kbase + j; }   // strict < : first-min semantics
        }
    }

    // Cross-wave argmin merge (wave order = ascending code index -> tie keeps lowest)
    smv[wv * 64 + lane] = bestv;
    smi[wv * 64 + lane] = besti;
    __syncthreads();
    if (threadIdx.x < 64) {
        float bv = smv[threadIdx.x];
        int   bi = smi[threadIdx.x];
#pragma unroll
        for (int w = 1; w < 4; ++w) {
            float v  = smv[w * 64 + threadIdx.x];
            int   ii = smi[w * 64 + threadIdx.x];
            if (v < bv) { bv = v; bi = ii; }
        }
        sidx[threadIdx.x] = bi;
        out_idx[t0 + threadIdx.x] = (float)bi;   // harness reads flat buffer as f32
        atomicAdd(&cs[bi], 1.0f);
    }
    __syncthreads();

    // Epilogue: z_q_st store (coalesced), loss partial, es segment-sum atomics
    const int k = sidx[lane];
    float lsum = 0.f;
    for (int d = wv; d < 256; d += 4) {
        float zv = As[d * 64 + lane];
        float eq = embed[k * 256 + d];           // gather, L2-resident (1 MB)
        out_zq[zbase + d * 1024 + lane] = zv + (eq - zv);
        float diff = zv - eq;
        lsum += diff * diff;
        atomicAdd(&es[k * 256 + d], zv);
    }
    for (int off = 32; off > 0; off >>= 1) lsum += __shfl_down(lsum, off);
    if (lane == 0) atomicAdd(loss_sum, lsum);
}

__global__ void vq_finalize_small(const float* __restrict__ cluster_size,
                                  const float* __restrict__ cs,
                                  const float* __restrict__ loss_sum,
                                  float* __restrict__ out_loss,
                                  float* __restrict__ out_ncs,
                                  float* __restrict__ csnorm)
{
    __shared__ float sred[1024];
    int k = threadIdx.x;
    float ncs = cluster_size[k] * DECAY + OMDECAY * cs[k];
    out_ncs[k] = ncs;
    sred[k] = ncs;
    __syncthreads();
    for (int s = 512; s > 0; s >>= 1) {
        if (k < s) sred[k] += sred[k + s];
        __syncthreads();
    }
    float n = sred[0];
    csnorm[k] = (ncs + EPSV) / (n + 1024.0f * EPSV) * n;
    if (k == 0) out_loss[0] = loss_sum[0] / 8388608.0f;
}

__global__ void vq_finalize_embed(const float* __restrict__ embed_avg,
                                  const float* __restrict__ es,
                                  const float* __restrict__ csnorm,
                                  float* __restrict__ out_embed,
                                  float* __restrict__ out_nea)
{
    int idx = blockIdx.x * 256 + threadIdx.x;    // 0..262143
    int k = idx >> 8;
    float nea = embed_avg[idx] * DECAY + OMDECAY * es[idx];
    out_nea[idx] = nea;
    out_embed[idx] = nea / csnorm[k];
}

extern "C" void kernel_launch(void* const* d_in, const int* in_sizes, int n_in,
                              void* d_out, int out_size, void* d_ws, size_t ws_size,
                              hipStream_t stream) {
    const float* z            = (const float*)d_in[0];
    const float* embed        = (const float*)d_in[1];
    const float* cluster_size = (const float*)d_in[2];
    const float* embed_avg    = (const float*)d_in[3];
    float* out = (float*)d_out;
    float* ws  = (float*)d_ws;

    float* embedT   = ws + 0;
    float* es       = ws + 262144;
    float* cs       = ws + 524288;
    float* enorm    = ws + 525312;
    float* csnorm   = ws + 526336;
    float* loss_sum = ws + 527360;

    // zero accumulators (es, cs, enorm, csnorm, loss)
    hipMemsetAsync((void*)es, 0, (size_t)(527364 - 262144) * sizeof(float), stream);

    transpose_embed<<<1024, 256, 0, stream>>>(embed, embedT);
    compute_enorm<<<256, 256, 0, stream>>>(embed, enorm);
    vq_main<<<512, 256, 0, stream>>>(z, embed, embedT, enorm,
                                     out, out + 8388608, es, cs, loss_sum);
    vq_finalize_small<<<1, 1024, 0, stream>>>(cluster_size, cs, loss_sum,
                                              out + 8421376, out + 8683521, csnorm);
    vq_finalize_embed<<<1024, 256, 0, stream>>>(embed_avg, es, csnorm,
                                                out + 8421377, out + 8684545);
}

// Round 2
// 1536.883 us; speedup vs baseline: 1.1796x; 1.1796x over previous
//
#include <hip/hip_runtime.h>
#include <stdint.h>

#define DECAY 0.99f
#define OMDECAY 0.01f
#define EPSV 1e-5f

// Problem: z (32,256,32,32) fp32; tokens N=32768, D=256, K=1024 codes.
// out (floats): zq[0,8388608) idx[8388608,8421376) loss[8421376]
//               new_embed[8421377,..) new_cs[8683521,..) new_ea[8684545,..)
// ws (dwords):
//   B_hi32   0        (131072)   1024x256 f16 packed 2/dword
//   B_lo32   131072   (131072)
//   A_hi32   262144   (4194304)  32768x256 f16, token-major
//   A_lo32   4456448  (4194304)
//   es       8650752  (262144)   fp32
//   cs       8912896  (1024)
//   loss     8913920  (1024, 1 used)
//   enorm    8914944  (1024)
//   csnorm   8915968  (1024)

typedef _Float16 half8 __attribute__((ext_vector_type(8)));
typedef float floatx4 __attribute__((ext_vector_type(4)));

typedef __attribute__((address_space(1))) const uint32_t gu32;
typedef __attribute__((address_space(3))) uint32_t lu32;

__device__ __forceinline__ void gld16(uint32_t* l, const uint32_t* g) {
    // async global->LDS, 16B per lane; LDS dest = uniform base + lane*16
    __builtin_amdgcn_global_load_lds((gu32*)g, (lu32*)l, 16, 0, 0);
}

__device__ __forceinline__ uint32_t pack_hl(float v) {
    _Float16 h = (_Float16)v;
    _Float16 lo = (_Float16)(v - (float)h);
    return (uint32_t)__builtin_bit_cast(unsigned short, h) |
           ((uint32_t)__builtin_bit_cast(unsigned short, lo) << 16);
}

// ---- prep: split embed (1024x256) into f16 hi/lo, row-major ----
__global__ void split_embed(const float* __restrict__ embed,
                            unsigned short* __restrict__ B_hi16,
                            unsigned short* __restrict__ B_lo16) {
    int idx = blockIdx.x * 256 + threadIdx.x;   // 0..262143
    float v = embed[idx];
    _Float16 h = (_Float16)v;
    _Float16 lo = (_Float16)(v - (float)h);
    B_hi16[idx] = __builtin_bit_cast(unsigned short, h);
    B_lo16[idx] = __builtin_bit_cast(unsigned short, lo);
}

// ---- prep: z (b,d,h,w) -> token-major f16 hi/lo A[t][d], via LDS transpose ----
__global__ void split_z(const float* __restrict__ z,
                        uint32_t* __restrict__ A_hi32,
                        uint32_t* __restrict__ A_lo32) {
    __shared__ uint32_t sp[32 * 258];   // [tok][258] packed hi|lo<<16, padded
    const int lane = threadIdx.x & 63;
    const int wv   = threadIdx.x >> 6;
    const int t0   = blockIdx.x * 32;
    const int b    = t0 >> 10;
    const int hw0  = t0 & 1023;

    for (int dd = wv; dd < 256; dd += 4) {
        if (lane < 32) {
            float v = z[b * 262144 + dd * 1024 + hw0 + lane];
            sp[lane * 258 + dd] = pack_hl(v);
        }
    }
    __syncthreads();
    for (int r = wv; r < 32; r += 4) {
#pragma unroll
        for (int h2 = 0; h2 < 2; ++h2) {
            int dpair = h2 * 64 + lane;              // dword 0..127 (2 d each)
            uint32_t u0 = sp[r * 258 + 2 * dpair];
            uint32_t u1 = sp[r * 258 + 2 * dpair + 1];
            A_hi32[(t0 + r) * 128 + dpair] = (u0 & 0xffffu) | (u1 << 16);
            A_lo32[(t0 + r) * 128 + dpair] = (u0 >> 16) | (u1 & 0xffff0000u);
        }
    }
}

__global__ void compute_enorm(const float* __restrict__ embed, float* __restrict__ enorm) {
    int wv = threadIdx.x >> 6;
    int lane = threadIdx.x & 63;
    int k = blockIdx.x * 4 + wv;
    const float* row = embed + k * 256;
    float s = 0.f;
#pragma unroll
    for (int j = 0; j < 4; ++j) {
        float v = row[lane + 64 * j];
        s += v * v;
    }
    for (int off = 32; off > 0; off >>= 1) s += __shfl_down(s, off);
    if (lane == 0) enorm[k] = s;
}

// ---- main: MFMA distance GEMM + fused argmin + epilogue ----
// 512 blocks x 256 thr. Block = 64 tokens x all 1024 codes.
// Wave w: codes [w*256,(w+1)*256) in 4 chunks of 64; d-chunks of 32 (1 K-step).
__global__ __launch_bounds__(256, 2) void vq_mfma(
    const float* __restrict__ z,
    const float* __restrict__ embed,
    const uint32_t* __restrict__ A_hi32,
    const uint32_t* __restrict__ A_lo32,
    const uint32_t* __restrict__ B_hi32,
    const uint32_t* __restrict__ B_lo32,
    const float* __restrict__ enorm,
    float* __restrict__ out_zq,
    float* __restrict__ out_idx,
    float* __restrict__ es,
    float* __restrict__ cs,
    float* __restrict__ loss_sum)
{
    __shared__ __align__(16) _Float16 AsH[64 * 32];    // 4 KB
    __shared__ __align__(16) _Float16 AsL[64 * 32];    // 4 KB
    __shared__ __align__(16) _Float16 BsH[256 * 32];   // 16 KB
    __shared__ __align__(16) _Float16 BsL[256 * 32];   // 16 KB
    __shared__ float smv[256];
    __shared__ int   smi[256];
    __shared__ int   sidx[64];

    const int lane = threadIdx.x & 63;
    const int w    = threadIdx.x >> 6;
    const int q    = lane >> 4;
    const int c16  = lane & 15;
    const int t0   = blockIdx.x * 64;
    const int lane4 = lane >> 2;           // staging: row within 16-row segment
    const int dd8   = (lane & 3) * 8;      // staging: d offset (8 halves)

    float bestv[16];
    int   besti[16];
#pragma unroll
    for (int s = 0; s < 16; ++s) { bestv[s] = 3.4e38f; besti[s] = 0; }

    for (int nc = 0; nc < 4; ++nc) {
        floatx4 acc[4][4];
#pragma unroll
        for (int i = 0; i < 4; ++i)
#pragma unroll
            for (int j = 0; j < 4; ++j)
                acc[i][j] = (floatx4){0.f, 0.f, 0.f, 0.f};

        for (int dc = 0; dc < 8; ++dc) {
            const int d0 = dc * 32;
            __syncthreads();   // prior frag reads done before overwrite
            // stage 40 KB: As hi/lo (4+4 segs), Bs hi/lo (16+16 segs), 1KB/seg
            for (int s = w; s < 40; s += 4) {
                if (s < 8) {
                    int ss = s & 3;
                    const uint32_t* base = (s < 4) ? A_hi32 : A_lo32;
                    uint32_t* dst = (uint32_t*)((s < 4) ? AsH : AsL) + ss * 256;
                    int tok = ss * 16 + lane4;
                    gld16(dst, base + (t0 + tok) * 128 + ((d0 + dd8) >> 1));
                } else {
                    int ss = (s - 8) & 15;
                    const uint32_t* base = (s < 24) ? B_hi32 : B_lo32;
                    uint32_t* dst = (uint32_t*)((s < 24) ? BsH : BsL) + ss * 256;
                    int row = ss * 16 + lane4;                 // 0..255
                    int code = ((row >> 6) << 8) + nc * 64 + (row & 63);
                    gld16(dst, base + code * 128 + ((d0 + dd8) >> 1));
                }
            }
            __syncthreads();   // drains vmcnt(0): staged data visible

            half8 aH[4], aL[4], bH[4], bL[4];
#pragma unroll
            for (int i = 0; i < 4; ++i) {
                int off = (i * 16 + c16) * 32 + q * 8;
                aH[i] = *(const half8*)(AsH + off);
                aL[i] = *(const half8*)(AsL + off);
            }
#pragma unroll
            for (int j = 0; j < 4; ++j) {
                int off = (w * 64 + j * 16 + c16) * 32 + q * 8;
                bH[j] = *(const half8*)(BsH + off);
                bL[j] = *(const half8*)(BsL + off);
            }
#pragma unroll
            for (int i = 0; i < 4; ++i)
#pragma unroll
                for (int j = 0; j < 4; ++j) {
                    acc[i][j] = __builtin_amdgcn_mfma_f32_16x16x32_f16(aH[i], bH[j], acc[i][j], 0, 0, 0);
                    acc[i][j] = __builtin_amdgcn_mfma_f32_16x16x32_f16(aH[i], bL[j], acc[i][j], 0, 0, 0);
                    acc[i][j] = __builtin_amdgcn_mfma_f32_16x16x32_f16(aL[i], bH[j], acc[i][j], 0, 0, 0);
                }
        }

        // score = ||e||^2 - 2*dot ; update per-token best (tie -> lowest code)
#pragma unroll
        for (int j = 0; j < 4; ++j) {
            int code = (w << 8) + nc * 64 + j * 16 + c16;
            float en = enorm[code];
#pragma unroll
            for (int i = 0; i < 4; ++i)
#pragma unroll
                for (int r = 0; r < 4; ++r) {
                    float sc = en - 2.0f * acc[i][j][r];
                    int slot = i * 4 + r;
                    if (sc < bestv[slot] || (sc == bestv[slot] && code < besti[slot])) {
                        bestv[slot] = sc; besti[slot] = code;
                    }
                }
        }
    }

    // butterfly argmin across the 16 lanes (c16) sharing each token
#pragma unroll
    for (int slot = 0; slot < 16; ++slot) {
        float v = bestv[slot]; int bi = besti[slot];
#pragma unroll
        for (int m = 1; m < 16; m <<= 1) {
            float ov = __shfl_xor(v, m);
            int   oi = __shfl_xor(bi, m);
            if (ov < v || (ov == v && oi < bi)) { v = ov; bi = oi; }
        }
        bestv[slot] = v; besti[slot] = bi;
    }
    if (c16 == 0) {
#pragma unroll
        for (int i = 0; i < 4; ++i)
#pragma unroll
            for (int r = 0; r < 4; ++r) {
                int ltok = i * 16 + q * 4 + r;
                smv[w * 64 + ltok] = bestv[i * 4 + r];
                smi[w * 64 + ltok] = besti[i * 4 + r];
            }
    }
    __syncthreads();

    // cross-wave merge (verified round-1 pattern) + tie-break on index
    if (threadIdx.x < 64) {
        float bv = smv[threadIdx.x];
        int   bi = smi[threadIdx.x];
#pragma unroll
        for (int ww = 1; ww < 4; ++ww) {
            float v  = smv[ww * 64 + threadIdx.x];
            int   ii = smi[ww * 64 + threadIdx.x];
            if (v < bv || (v == bv && ii < bi)) { bv = v; bi = ii; }
        }
        sidx[threadIdx.x] = bi;
        out_idx[t0 + threadIdx.x] = (float)bi;
        atomicAdd(&cs[bi], 1.0f);
    }
    __syncthreads();

    // epilogue: z_q store, loss, es segment sums (round-1 verified, z from global)
    const int b_idx = t0 >> 10;
    const int hw0   = t0 & 1023;
    const int zbase = b_idx * 262144 + hw0;
    const int k = sidx[lane];
    float lsum = 0.f;
    for (int d = w; d < 256; d += 4) {
        float zv = z[zbase + d * 1024 + lane];
        float eq = embed[k * 256 + d];
        out_zq[zbase + d * 1024 + lane] = zv + (eq - zv);
        float diff = zv - eq;
        lsum += diff * diff;
        atomicAdd(&es[k * 256 + d], zv);
    }
    for (int off = 32; off > 0; off >>= 1) lsum += __shfl_down(lsum, off);
    if (lane == 0) atomicAdd(loss_sum, lsum);
}

__global__ void vq_finalize_small(const float* __restrict__ cluster_size,
                                  const float* __restrict__ cs,
                                  const float* __restrict__ loss_sum,
                                  float* __restrict__ out_loss,
                                  float* __restrict__ out_ncs,
                                  float* __restrict__ csnorm)
{
    __shared__ float sred[1024];
    int k = threadIdx.x;
    float ncs = cluster_size[k] * DECAY + OMDECAY * cs[k];
    out_ncs[k] = ncs;
    sred[k] = ncs;
    __syncthreads();
    for (int s = 512; s > 0; s >>= 1) {
        if (k < s) sred[k] += sred[k + s];
        __syncthreads();
    }
    float n = sred[0];
    csnorm[k] = (ncs + EPSV) / (n + 1024.0f * EPSV) * n;
    if (k == 0) out_loss[0] = loss_sum[0] / 8388608.0f;
}

__global__ void vq_finalize_embed(const float* __restrict__ embed_avg,
                                  const float* __restrict__ es,
                                  const float* __restrict__ csnorm,
                                  float* __restrict__ out_embed,
                                  float* __restrict__ out_nea)
{
    int idx = blockIdx.x * 256 + threadIdx.x;
    int k = idx >> 8;
    float nea = embed_avg[idx] * DECAY + OMDECAY * es[idx];
    out_nea[idx] = nea;
    out_embed[idx] = nea / csnorm[k];
}

extern "C" void kernel_launch(void* const* d_in, const int* in_sizes, int n_in,
                              void* d_out, int out_size, void* d_ws, size_t ws_size,
                              hipStream_t stream) {
    const float* z            = (const float*)d_in[0];
    const float* embed        = (const float*)d_in[1];
    const float* cluster_size = (const float*)d_in[2];
    const float* embed_avg    = (const float*)d_in[3];
    float* out = (float*)d_out;
    uint32_t* ws32 = (uint32_t*)d_ws;

    uint32_t* B_hi32 = ws32 + 0;
    uint32_t* B_lo32 = ws32 + 131072;
    uint32_t* A_hi32 = ws32 + 262144;
    uint32_t* A_lo32 = ws32 + 4456448;
    float* es       = (float*)(ws32 + 8650752);
    float* cs       = (float*)(ws32 + 8912896);
    float* loss_sum = (float*)(ws32 + 8913920);
    float* enorm    = (float*)(ws32 + 8914944);
    float* csnorm   = (float*)(ws32 + 8915968);

    // zero es + cs + loss (contiguous)
    hipMemsetAsync((void*)es, 0, (size_t)(262144 + 1024 + 1024) * 4, stream);

    split_embed<<<1024, 256, 0, stream>>>(embed, (unsigned short*)B_hi32, (unsigned short*)B_lo32);
    split_z<<<1024, 256, 0, stream>>>(z, A_hi32, A_lo32);
    compute_enorm<<<256, 256, 0, stream>>>(embed, enorm);
    vq_mfma<<<512, 256, 0, stream>>>(z, embed, A_hi32, A_lo32, B_hi32, B_lo32, enorm,
                                     out, out + 8388608, es, cs, loss_sum);
    vq_finalize_small<<<1, 1024, 0, stream>>>(cluster_size, cs, loss_sum,
                                              out + 8421376, out + 8683521, csnorm);
    vq_finalize_embed<<<1024, 256, 0, stream>>>(embed_avg, es, csnorm,
                                                out + 8421377, out + 8684545);
}

// Round 3
// 649.911 us; speedup vs baseline: 2.7894x; 2.3648x over previous
//
#include <hip/hip_runtime.h>
#include <stdint.h>

#define DECAY 0.99f
#define OMDECAY 0.01f
#define EPSV 1e-5f

// Problem: z (32,256,32,32) fp32; tokens N=32768, D=256, K=1024 codes.
// out (floats): zq[0,8388608) idx[8388608,8421376) loss[8421376]
//               new_embed[8421377,..) new_cs[8683521,..) new_ea[8684545,..)
// ws (dwords):
//   B_hi32   0        (131072)   1024x256 f16 packed 2/dword
//   B_lo32   131072   (131072)
//   A_hi32   262144   (4194304)  32768x256 f16, token-major
//   A_lo32   4456448  (4194304)
//   perm     8650752  (32768)    int, tokens sorted by code
//   offsets  8683520  (1024)     int, segment starts
//   cursor   8684544  (1024)     int, atomic cursors
//   cs       8912896  (1024)     fp32 histogram
//   loss     8913920  (1024, 1 used)
//   enorm    8914944  (1024)
//   csnorm   8915968  (1024)

typedef _Float16 half8 __attribute__((ext_vector_type(8)));
typedef float floatx4 __attribute__((ext_vector_type(4)));

typedef __attribute__((address_space(1))) const uint32_t gu32;
typedef __attribute__((address_space(3))) uint32_t lu32;

__device__ __forceinline__ void gld16(uint32_t* l, const uint32_t* g) {
    __builtin_amdgcn_global_load_lds((gu32*)g, (lu32*)l, 16, 0, 0);
}

__device__ __forceinline__ uint32_t pack_hl(float v) {
    _Float16 h = (_Float16)v;
    _Float16 lo = (_Float16)(v - (float)h);
    return (uint32_t)__builtin_bit_cast(unsigned short, h) |
           ((uint32_t)__builtin_bit_cast(unsigned short, lo) << 16);
}

__device__ __forceinline__ float unpack_sum(uint32_t hi, uint32_t lo, int sel) {
    unsigned short uh = sel ? (unsigned short)(hi >> 16) : (unsigned short)(hi & 0xffffu);
    unsigned short ul = sel ? (unsigned short)(lo >> 16) : (unsigned short)(lo & 0xffffu);
    return (float)__builtin_bit_cast(_Float16, uh) + (float)__builtin_bit_cast(_Float16, ul);
}

// ---- prep: split embed (1024x256) into f16 hi/lo, row-major ----
__global__ void split_embed(const float* __restrict__ embed,
                            unsigned short* __restrict__ B_hi16,
                            unsigned short* __restrict__ B_lo16) {
    int idx = blockIdx.x * 256 + threadIdx.x;
    float v = embed[idx];
    _Float16 h = (_Float16)v;
    _Float16 lo = (_Float16)(v - (float)h);
    B_hi16[idx] = __builtin_bit_cast(unsigned short, h);
    B_lo16[idx] = __builtin_bit_cast(unsigned short, lo);
}

// ---- prep: z (b,d,h,w) -> token-major f16 hi/lo A[t][d], via LDS transpose ----
__global__ void split_z(const float* __restrict__ z,
                        uint32_t* __restrict__ A_hi32,
                        uint32_t* __restrict__ A_lo32) {
    __shared__ uint32_t sp[32 * 258];
    const int lane = threadIdx.x & 63;
    const int wv   = threadIdx.x >> 6;
    const int t0   = blockIdx.x * 32;
    const int b    = t0 >> 10;
    const int hw0  = t0 & 1023;

    for (int dd = wv; dd < 256; dd += 4) {
        if (lane < 32) {
            float v = z[b * 262144 + dd * 1024 + hw0 + lane];
            sp[lane * 258 + dd] = pack_hl(v);
        }
    }
    __syncthreads();
    for (int r = wv; r < 32; r += 4) {
#pragma unroll
        for (int h2 = 0; h2 < 2; ++h2) {
            int dpair = h2 * 64 + lane;
            uint32_t u0 = sp[r * 258 + 2 * dpair];
            uint32_t u1 = sp[r * 258 + 2 * dpair + 1];
            A_hi32[(t0 + r) * 128 + dpair] = (u0 & 0xffffu) | (u1 << 16);
            A_lo32[(t0 + r) * 128 + dpair] = (u0 >> 16) | (u1 & 0xffff0000u);
        }
    }
}

__global__ void compute_enorm(const float* __restrict__ embed, float* __restrict__ enorm) {
    int wv = threadIdx.x >> 6;
    int lane = threadIdx.x & 63;
    int k = blockIdx.x * 4 + wv;
    const float* row = embed + k * 256;
    float s = 0.f;
#pragma unroll
    for (int j = 0; j < 4; ++j) {
        float v = row[lane + 64 * j];
        s += v * v;
    }
    for (int off = 32; off > 0; off >>= 1) s += __shfl_down(s, off);
    if (lane == 0) enorm[k] = s;
}

// ---- main: MFMA distance GEMM + fused argmin + zq/loss epilogue ----
__global__ __launch_bounds__(256, 2) void vq_mfma(
    const float* __restrict__ z,
    const float* __restrict__ embed,
    const uint32_t* __restrict__ A_hi32,
    const uint32_t* __restrict__ A_lo32,
    const uint32_t* __restrict__ B_hi32,
    const uint32_t* __restrict__ B_lo32,
    const float* __restrict__ enorm,
    float* __restrict__ out_zq,
    float* __restrict__ out_idx,
    float* __restrict__ cs,
    float* __restrict__ loss_sum)
{
    __shared__ __align__(16) _Float16 AsH[64 * 32];
    __shared__ __align__(16) _Float16 AsL[64 * 32];
    __shared__ __align__(16) _Float16 BsH[256 * 32];
    __shared__ __align__(16) _Float16 BsL[256 * 32];
    __shared__ float smv[256];
    __shared__ int   smi[256];
    __shared__ int   sidx[64];

    const int lane = threadIdx.x & 63;
    const int w    = threadIdx.x >> 6;
    const int q    = lane >> 4;
    const int c16  = lane & 15;
    const int t0   = blockIdx.x * 64;
    const int lane4 = lane >> 2;
    const int dd8   = (lane & 3) * 8;

    float bestv[16];
    int   besti[16];
#pragma unroll
    for (int s = 0; s < 16; ++s) { bestv[s] = 3.4e38f; besti[s] = 0; }

    for (int nc = 0; nc < 4; ++nc) {
        floatx4 acc[4][4];
#pragma unroll
        for (int i = 0; i < 4; ++i)
#pragma unroll
            for (int j = 0; j < 4; ++j)
                acc[i][j] = (floatx4){0.f, 0.f, 0.f, 0.f};

        for (int dc = 0; dc < 8; ++dc) {
            const int d0 = dc * 32;
            __syncthreads();
            for (int s = w; s < 40; s += 4) {
                if (s < 8) {
                    int ss = s & 3;
                    const uint32_t* base = (s < 4) ? A_hi32 : A_lo32;
                    uint32_t* dst = (uint32_t*)((s < 4) ? AsH : AsL) + ss * 256;
                    int tok = ss * 16 + lane4;
                    gld16(dst, base + (t0 + tok) * 128 + ((d0 + dd8) >> 1));
                } else {
                    int ss = (s - 8) & 15;
                    const uint32_t* base = (s < 24) ? B_hi32 : B_lo32;
                    uint32_t* dst = (uint32_t*)((s < 24) ? BsH : BsL) + ss * 256;
                    int row = ss * 16 + lane4;
                    int code = ((row >> 6) << 8) + nc * 64 + (row & 63);
                    gld16(dst, base + code * 128 + ((d0 + dd8) >> 1));
                }
            }
            __syncthreads();

            half8 aH[4], aL[4], bH[4], bL[4];
#pragma unroll
            for (int i = 0; i < 4; ++i) {
                int off = (i * 16 + c16) * 32 + q * 8;
                aH[i] = *(const half8*)(AsH + off);
                aL[i] = *(const half8*)(AsL + off);
            }
#pragma unroll
            for (int j = 0; j < 4; ++j) {
                int off = (w * 64 + j * 16 + c16) * 32 + q * 8;
                bH[j] = *(const half8*)(BsH + off);
                bL[j] = *(const half8*)(BsL + off);
            }
#pragma unroll
            for (int i = 0; i < 4; ++i)
#pragma unroll
                for (int j = 0; j < 4; ++j) {
                    acc[i][j] = __builtin_amdgcn_mfma_f32_16x16x32_f16(aH[i], bH[j], acc[i][j], 0, 0, 0);
                    acc[i][j] = __builtin_amdgcn_mfma_f32_16x16x32_f16(aH[i], bL[j], acc[i][j], 0, 0, 0);
                    acc[i][j] = __builtin_amdgcn_mfma_f32_16x16x32_f16(aL[i], bH[j], acc[i][j], 0, 0, 0);
                }
        }

#pragma unroll
        for (int j = 0; j < 4; ++j) {
            int code = (w << 8) + nc * 64 + j * 16 + c16;
            float en = enorm[code];
#pragma unroll
            for (int i = 0; i < 4; ++i)
#pragma unroll
                for (int r = 0; r < 4; ++r) {
                    float sc = en - 2.0f * acc[i][j][r];
                    int slot = i * 4 + r;
                    if (sc < bestv[slot] || (sc == bestv[slot] && code < besti[slot])) {
                        bestv[slot] = sc; besti[slot] = code;
                    }
                }
        }
    }

#pragma unroll
    for (int slot = 0; slot < 16; ++slot) {
        float v = bestv[slot]; int bi = besti[slot];
#pragma unroll
        for (int m = 1; m < 16; m <<= 1) {
            float ov = __shfl_xor(v, m);
            int   oi = __shfl_xor(bi, m);
            if (ov < v || (ov == v && oi < bi)) { v = ov; bi = oi; }
        }
        bestv[slot] = v; besti[slot] = bi;
    }
    if (c16 == 0) {
#pragma unroll
        for (int i = 0; i < 4; ++i)
#pragma unroll
            for (int r = 0; r < 4; ++r) {
                int ltok = i * 16 + q * 4 + r;
                smv[w * 64 + ltok] = bestv[i * 4 + r];
                smi[w * 64 + ltok] = besti[i * 4 + r];
            }
    }
    __syncthreads();

    if (threadIdx.x < 64) {
        float bv = smv[threadIdx.x];
        int   bi = smi[threadIdx.x];
#pragma unroll
        for (int ww = 1; ww < 4; ++ww) {
            float v  = smv[ww * 64 + threadIdx.x];
            int   ii = smi[ww * 64 + threadIdx.x];
            if (v < bv || (v == bv && ii < bi)) { bv = v; bi = ii; }
        }
        sidx[threadIdx.x] = bi;
        out_idx[t0 + threadIdx.x] = (float)bi;
        atomicAdd(&cs[bi], 1.0f);
    }
    __syncthreads();

    // epilogue: z_q store + loss only (NO es atomics)
    const int b_idx = t0 >> 10;
    const int hw0   = t0 & 1023;
    const int zbase = b_idx * 262144 + hw0;
    const int k = sidx[lane];
    float lsum = 0.f;
    for (int d = w; d < 256; d += 4) {
        float zv = z[zbase + d * 1024 + lane];
        float eq = embed[k * 256 + d];
        out_zq[zbase + d * 1024 + lane] = zv + (eq - zv);
        float diff = zv - eq;
        lsum += diff * diff;
    }
    for (int off = 32; off > 0; off >>= 1) lsum += __shfl_down(lsum, off);
    if (lane == 0) atomicAdd(loss_sum, lsum);
}

// ---- finalize: loss, new_cluster, csnorm, prefix-scan of counts ----
__global__ void vq_finalize_small(const float* __restrict__ cluster_size,
                                  const float* __restrict__ cs,
                                  const float* __restrict__ loss_sum,
                                  float* __restrict__ out_loss,
                                  float* __restrict__ out_ncs,
                                  float* __restrict__ csnorm,
                                  int* __restrict__ offsets,
                                  int* __restrict__ cursor)
{
    __shared__ float sred[1024];
    __shared__ float sscan[1024];
    int k = threadIdx.x;
    float cnt = cs[k];
    float ncs = cluster_size[k] * DECAY + OMDECAY * cnt;
    out_ncs[k] = ncs;
    sred[k] = ncs;
    sscan[k] = cnt;
    __syncthreads();
    // Hillis-Steele inclusive scan over counts
    for (int off = 1; off < 1024; off <<= 1) {
        float add = (k >= off) ? sscan[k - off] : 0.f;
        __syncthreads();
        sscan[k] += add;
        __syncthreads();
    }
    int excl = __float2int_rn(sscan[k] - cnt);
    offsets[k] = excl;
    cursor[k]  = excl;
    // tree reduce ncs for n
    for (int s = 512; s > 0; s >>= 1) {
        if (k < s) sred[k] += sred[k + s];
        __syncthreads();
    }
    float n = sred[0];
    csnorm[k] = (ncs + EPSV) / (n + 1024.0f * EPSV) * n;
    if (k == 0) out_loss[0] = loss_sum[0] / 8388608.0f;
}

// ---- counting-sort scatter: perm = tokens grouped by code ----
__global__ void scatter_perm(const float* __restrict__ out_idx,
                             int* __restrict__ cursor,
                             int* __restrict__ perm)
{
    int t = blockIdx.x * 256 + threadIdx.x;   // 0..32767
    int code = (int)out_idx[t];
    int pos = atomicAdd(&cursor[code], 1);
    perm[pos] = t;
}

// ---- segmented sum: es per code from token-major f16 hi/lo, fused EMA ----
// 1024 blocks (one per code) x 128 threads (thread j = dword j = dims 2j,2j+1)
__global__ void compute_es(const uint32_t* __restrict__ A_hi32,
                           const uint32_t* __restrict__ A_lo32,
                           const int* __restrict__ perm,
                           const int* __restrict__ offsets,
                           const float* __restrict__ cs,
                           const float* __restrict__ embed_avg,
                           const float* __restrict__ csnorm,
                           float* __restrict__ out_embed,
                           float* __restrict__ out_nea)
{
    const int k = blockIdx.x;
    const int j = threadIdx.x;           // 0..127
    const int start = offsets[k];
    const int len = __float2int_rn(cs[k]);
    float s0 = 0.f, s1 = 0.f;
    for (int i = 0; i < len; ++i) {
        int t = perm[start + i];         // uniform -> broadcast
        uint32_t uh = A_hi32[t * 128 + j];
        uint32_t ul = A_lo32[t * 128 + j];
        s0 += unpack_sum(uh, ul, 0);
        s1 += unpack_sum(uh, ul, 1);
    }
    const int d0 = k * 256 + 2 * j;
    const float cn = csnorm[k];
    float nea0 = embed_avg[d0]     * DECAY + OMDECAY * s0;
    float nea1 = embed_avg[d0 + 1] * DECAY + OMDECAY * s1;
    out_nea[d0]       = nea0;
    out_nea[d0 + 1]   = nea1;
    out_embed[d0]     = nea0 / cn;
    out_embed[d0 + 1] = nea1 / cn;
}

extern "C" void kernel_launch(void* const* d_in, const int* in_sizes, int n_in,
                              void* d_out, int out_size, void* d_ws, size_t ws_size,
                              hipStream_t stream) {
    const float* z            = (const float*)d_in[0];
    const float* embed        = (const float*)d_in[1];
    const float* cluster_size = (const float*)d_in[2];
    const float* embed_avg    = (const float*)d_in[3];
    float* out = (float*)d_out;
    uint32_t* ws32 = (uint32_t*)d_ws;

    uint32_t* B_hi32 = ws32 + 0;
    uint32_t* B_lo32 = ws32 + 131072;
    uint32_t* A_hi32 = ws32 + 262144;
    uint32_t* A_lo32 = ws32 + 4456448;
    int* perm        = (int*)(ws32 + 8650752);
    int* offsets     = (int*)(ws32 + 8683520);
    int* cursor      = (int*)(ws32 + 8684544);
    float* cs        = (float*)(ws32 + 8912896);
    float* loss_sum  = (float*)(ws32 + 8913920);
    float* enorm     = (float*)(ws32 + 8914944);
    float* csnorm    = (float*)(ws32 + 8915968);

    // zero cs + loss
    hipMemsetAsync((void*)cs, 0, (size_t)2048 * 4, stream);

    split_embed<<<1024, 256, 0, stream>>>(embed, (unsigned short*)B_hi32, (unsigned short*)B_lo32);
    split_z<<<1024, 256, 0, stream>>>(z, A_hi32, A_lo32);
    compute_enorm<<<256, 256, 0, stream>>>(embed, enorm);
    vq_mfma<<<512, 256, 0, stream>>>(z, embed, A_hi32, A_lo32, B_hi32, B_lo32, enorm,
                                     out, out + 8388608, cs, loss_sum);
    vq_finalize_small<<<1, 1024, 0, stream>>>(cluster_size, cs, loss_sum,
                                              out + 8421376, out + 8683521, csnorm,
                                              offsets, cursor);
    scatter_perm<<<128, 256, 0, stream>>>(out + 8388608, cursor, perm);
    compute_es<<<1024, 128, 0, stream>>>(A_hi32, A_lo32, perm, offsets, cs,
                                         embed_avg, csnorm,
                                         out + 8421377, out + 8684545);
}

// Round 4
// 291.616 us; speedup vs baseline: 6.2167x; 2.2287x over previous
//
#include <hip/hip_runtime.h>
#include <stdint.h>

#define DECAY 0.99f
#define OMDECAY 0.01f
#define EPSV 1e-5f

// Problem: z (32,256,32,32) fp32; tokens N=32768, D=256, K=1024 codes.
// out (floats): zq[0,8388608) idx[8388608,8421376) loss[8421376]
//               new_embed[8421377,..) new_cs[8683521,..) new_ea[8684545,..)
// ws (dwords):
//   B_hi32   0        (131072)   1024x256 f16 packed 2/dword   } es (262144 fp32)
//   B_lo32   131072   (131072)                                 } reused after vq_mfma
//   A_hi32   262144   (4194304)  32768x256 f16, token-major
//   A_lo32   4456448  (4194304)
//   perm     8650752  (32768)    int, tokens sorted by code
//   offsets  8683520  (1024)     int, segment starts
//   cursor   8684544  (1024)     int, atomic cursors
//   cs       8912896  (1024)     fp32 histogram
//   loss     8913920  (1024, 1 used)
//   enorm    8914944  (1024)
//   csnorm   8915968  (1024)

typedef _Float16 half8 __attribute__((ext_vector_type(8)));
typedef float floatx4 __attribute__((ext_vector_type(4)));

typedef __attribute__((address_space(1))) const uint32_t gu32;
typedef __attribute__((address_space(3))) uint32_t lu32;

__device__ __forceinline__ void gld16(uint32_t* l, const uint32_t* g) {
    __builtin_amdgcn_global_load_lds((gu32*)g, (lu32*)l, 16, 0, 0);
}

__device__ __forceinline__ uint32_t pack_hl(float v) {
    _Float16 h = (_Float16)v;
    _Float16 lo = (_Float16)(v - (float)h);
    return (uint32_t)__builtin_bit_cast(unsigned short, h) |
           ((uint32_t)__builtin_bit_cast(unsigned short, lo) << 16);
}

__device__ __forceinline__ float unpack_sum(uint32_t hi, uint32_t lo, int sel) {
    unsigned short uh = sel ? (unsigned short)(hi >> 16) : (unsigned short)(hi & 0xffffu);
    unsigned short ul = sel ? (unsigned short)(lo >> 16) : (unsigned short)(lo & 0xffffu);
    return (float)__builtin_bit_cast(_Float16, uh) + (float)__builtin_bit_cast(_Float16, ul);
}

// ---- prep: split embed (1024x256) into f16 hi/lo, row-major ----
__global__ void split_embed(const float* __restrict__ embed,
                            unsigned short* __restrict__ B_hi16,
                            unsigned short* __restrict__ B_lo16) {
    int idx = blockIdx.x * 256 + threadIdx.x;
    float v = embed[idx];
    _Float16 h = (_Float16)v;
    _Float16 lo = (_Float16)(v - (float)h);
    B_hi16[idx] = __builtin_bit_cast(unsigned short, h);
    B_lo16[idx] = __builtin_bit_cast(unsigned short, lo);
}

// ---- prep: z (b,d,h,w) -> token-major f16 hi/lo A[t][d], via LDS transpose ----
__global__ void split_z(const float* __restrict__ z,
                        uint32_t* __restrict__ A_hi32,
                        uint32_t* __restrict__ A_lo32) {
    __shared__ uint32_t sp[32 * 258];
    const int lane = threadIdx.x & 63;
    const int wv   = threadIdx.x >> 6;
    const int t0   = blockIdx.x * 32;
    const int b    = t0 >> 10;
    const int hw0  = t0 & 1023;

    for (int dd = wv; dd < 256; dd += 4) {
        if (lane < 32) {
            float v = z[b * 262144 + dd * 1024 + hw0 + lane];
            sp[lane * 258 + dd] = pack_hl(v);
        }
    }
    __syncthreads();
    for (int r = wv; r < 32; r += 4) {
#pragma unroll
        for (int h2 = 0; h2 < 2; ++h2) {
            int dpair = h2 * 64 + lane;
            uint32_t u0 = sp[r * 258 + 2 * dpair];
            uint32_t u1 = sp[r * 258 + 2 * dpair + 1];
            A_hi32[(t0 + r) * 128 + dpair] = (u0 & 0xffffu) | (u1 << 16);
            A_lo32[(t0 + r) * 128 + dpair] = (u0 >> 16) | (u1 & 0xffff0000u);
        }
    }
}

__global__ void compute_enorm(const float* __restrict__ embed, float* __restrict__ enorm) {
    int wv = threadIdx.x >> 6;
    int lane = threadIdx.x & 63;
    int k = blockIdx.x * 4 + wv;
    const float* row = embed + k * 256;
    float s = 0.f;
#pragma unroll
    for (int j = 0; j < 4; ++j) {
        float v = row[lane + 64 * j];
        s += v * v;
    }
    for (int off = 32; off > 0; off >>= 1) s += __shfl_down(s, off);
    if (lane == 0) enorm[k] = s;
}

// ---- main: MFMA distance GEMM + fused argmin + zq/loss epilogue ----
__global__ __launch_bounds__(256, 2) void vq_mfma(
    const float* __restrict__ z,
    const float* __restrict__ embed,
    const uint32_t* __restrict__ A_hi32,
    const uint32_t* __restrict__ A_lo32,
    const uint32_t* __restrict__ B_hi32,
    const uint32_t* __restrict__ B_lo32,
    const float* __restrict__ enorm,
    float* __restrict__ out_zq,
    float* __restrict__ out_idx,
    float* __restrict__ cs,
    float* __restrict__ loss_sum)
{
    __shared__ __align__(16) _Float16 AsH[64 * 32];
    __shared__ __align__(16) _Float16 AsL[64 * 32];
    __shared__ __align__(16) _Float16 BsH[256 * 32];
    __shared__ __align__(16) _Float16 BsL[256 * 32];
    __shared__ float smv[256];
    __shared__ int   smi[256];
    __shared__ int   sidx[64];

    const int lane = threadIdx.x & 63;
    const int w    = threadIdx.x >> 6;
    const int q    = lane >> 4;
    const int c16  = lane & 15;
    const int t0   = blockIdx.x * 64;
    const int lane4 = lane >> 2;
    const int dd8   = (lane & 3) * 8;

    float bestv[16];
    int   besti[16];
#pragma unroll
    for (int s = 0; s < 16; ++s) { bestv[s] = 3.4e38f; besti[s] = 0; }

    for (int nc = 0; nc < 4; ++nc) {
        floatx4 acc[4][4];
#pragma unroll
        for (int i = 0; i < 4; ++i)
#pragma unroll
            for (int j = 0; j < 4; ++j)
                acc[i][j] = (floatx4){0.f, 0.f, 0.f, 0.f};

        for (int dc = 0; dc < 8; ++dc) {
            const int d0 = dc * 32;
            __syncthreads();
            for (int s = w; s < 40; s += 4) {
                if (s < 8) {
                    int ss = s & 3;
                    const uint32_t* base = (s < 4) ? A_hi32 : A_lo32;
                    uint32_t* dst = (uint32_t*)((s < 4) ? AsH : AsL) + ss * 256;
                    int tok = ss * 16 + lane4;
                    gld16(dst, base + (t0 + tok) * 128 + ((d0 + dd8) >> 1));
                } else {
                    int ss = (s - 8) & 15;
                    const uint32_t* base = (s < 24) ? B_hi32 : B_lo32;
                    uint32_t* dst = (uint32_t*)((s < 24) ? BsH : BsL) + ss * 256;
                    int row = ss * 16 + lane4;
                    int code = ((row >> 6) << 8) + nc * 64 + (row & 63);
                    gld16(dst, base + code * 128 + ((d0 + dd8) >> 1));
                }
            }
            __syncthreads();

            half8 aH[4], aL[4], bH[4], bL[4];
#pragma unroll
            for (int i = 0; i < 4; ++i) {
                int off = (i * 16 + c16) * 32 + q * 8;
                aH[i] = *(const half8*)(AsH + off);
                aL[i] = *(const half8*)(AsL + off);
            }
#pragma unroll
            for (int j = 0; j < 4; ++j) {
                int off = (w * 64 + j * 16 + c16) * 32 + q * 8;
                bH[j] = *(const half8*)(BsH + off);
                bL[j] = *(const half8*)(BsL + off);
            }
#pragma unroll
            for (int i = 0; i < 4; ++i)
#pragma unroll
                for (int j = 0; j < 4; ++j) {
                    acc[i][j] = __builtin_amdgcn_mfma_f32_16x16x32_f16(aH[i], bH[j], acc[i][j], 0, 0, 0);
                    acc[i][j] = __builtin_amdgcn_mfma_f32_16x16x32_f16(aH[i], bL[j], acc[i][j], 0, 0, 0);
                    acc[i][j] = __builtin_amdgcn_mfma_f32_16x16x32_f16(aL[i], bH[j], acc[i][j], 0, 0, 0);
                }
        }

#pragma unroll
        for (int j = 0; j < 4; ++j) {
            int code = (w << 8) + nc * 64 + j * 16 + c16;
            float en = enorm[code];
#pragma unroll
            for (int i = 0; i < 4; ++i)
#pragma unroll
                for (int r = 0; r < 4; ++r) {
                    float sc = en - 2.0f * acc[i][j][r];
                    int slot = i * 4 + r;
                    if (sc < bestv[slot] || (sc == bestv[slot] && code < besti[slot])) {
                        bestv[slot] = sc; besti[slot] = code;
                    }
                }
        }
    }

#pragma unroll
    for (int slot = 0; slot < 16; ++slot) {
        float v = bestv[slot]; int bi = besti[slot];
#pragma unroll
        for (int m = 1; m < 16; m <<= 1) {
            float ov = __shfl_xor(v, m);
            int   oi = __shfl_xor(bi, m);
            if (ov < v || (ov == v && oi < bi)) { v = ov; bi = oi; }
        }
        bestv[slot] = v; besti[slot] = bi;
    }
    if (c16 == 0) {
#pragma unroll
        for (int i = 0; i < 4; ++i)
#pragma unroll
            for (int r = 0; r < 4; ++r) {
                int ltok = i * 16 + q * 4 + r;
                smv[w * 64 + ltok] = bestv[i * 4 + r];
                smi[w * 64 + ltok] = besti[i * 4 + r];
            }
    }
    __syncthreads();

    if (threadIdx.x < 64) {
        float bv = smv[threadIdx.x];
        int   bi = smi[threadIdx.x];
#pragma unroll
        for (int ww = 1; ww < 4; ++ww) {
            float v  = smv[ww * 64 + threadIdx.x];
            int   ii = smi[ww * 64 + threadIdx.x];
            if (v < bv || (v == bv && ii < bi)) { bv = v; bi = ii; }
        }
        sidx[threadIdx.x] = bi;
        out_idx[t0 + threadIdx.x] = (float)bi;
        atomicAdd(&cs[bi], 1.0f);
    }
    __syncthreads();

    // epilogue: z_q store + loss only (NO es atomics)
    const int b_idx = t0 >> 10;
    const int hw0   = t0 & 1023;
    const int zbase = b_idx * 262144 + hw0;
    const int k = sidx[lane];
    float lsum = 0.f;
    for (int d = w; d < 256; d += 4) {
        float zv = z[zbase + d * 1024 + lane];
        float eq = embed[k * 256 + d];
        out_zq[zbase + d * 1024 + lane] = zv + (eq - zv);
        float diff = zv - eq;
        lsum += diff * diff;
    }
    for (int off = 32; off > 0; off >>= 1) lsum += __shfl_down(lsum, off);
    if (lane == 0) atomicAdd(loss_sum, lsum);
}

// ---- finalize: loss, new_cluster, csnorm, prefix-scan of counts ----
__global__ void vq_finalize_small(const float* __restrict__ cluster_size,
                                  const float* __restrict__ cs,
                                  const float* __restrict__ loss_sum,
                                  float* __restrict__ out_loss,
                                  float* __restrict__ out_ncs,
                                  float* __restrict__ csnorm,
                                  int* __restrict__ offsets,
                                  int* __restrict__ cursor)
{
    __shared__ float sred[1024];
    __shared__ float sscan[1024];
    int k = threadIdx.x;
    float cnt = cs[k];
    float ncs = cluster_size[k] * DECAY + OMDECAY * cnt;
    out_ncs[k] = ncs;
    sred[k] = ncs;
    sscan[k] = cnt;
    __syncthreads();
    for (int off = 1; off < 1024; off <<= 1) {
        float add = (k >= off) ? sscan[k - off] : 0.f;
        __syncthreads();
        sscan[k] += add;
        __syncthreads();
    }
    int excl = __float2int_rn(sscan[k] - cnt);
    offsets[k] = excl;
    cursor[k]  = excl;
    for (int s = 512; s > 0; s >>= 1) {
        if (k < s) sred[k] += sred[k + s];
        __syncthreads();
    }
    float n = sred[0];
    csnorm[k] = (ncs + EPSV) / (n + 1024.0f * EPSV) * n;
    if (k == 0) out_loss[0] = loss_sum[0] / 8388608.0f;
}

// ---- counting-sort scatter: perm = tokens grouped by code ----
__global__ void scatter_perm(const float* __restrict__ out_idx,
                             int* __restrict__ cursor,
                             int* __restrict__ perm)
{
    int t = blockIdx.x * 256 + threadIdx.x;
    int code = (int)out_idx[t];
    int pos = atomicAdd(&cursor[code], 1);
    perm[pos] = t;
}

// ---- chunked segmented sum over the SORTED token list ----
// 1024 blocks x 128 threads; block = 32 perm entries; thread j = dword j.
// Segment boundaries are wave-uniform; flushes are coalesced atomics.
__global__ void es_sum(const uint32_t* __restrict__ A_hi32,
                       const uint32_t* __restrict__ A_lo32,
                       const int* __restrict__ perm,
                       const float* __restrict__ out_idx,
                       float* __restrict__ es)
{
    __shared__ int sperm[32];
    __shared__ int scode[32];
    const int base = blockIdx.x * 32;
    const int j = threadIdx.x;           // 0..127
    if (j < 32) {
        int t = perm[base + j];
        sperm[j] = t;
        scode[j] = (int)out_idx[t];
    }
    __syncthreads();

    float s0 = 0.f, s1 = 0.f;
    int cur = scode[0];
    uint32_t puh[2], pul[2];
    {
        int ta = sperm[0], tb = sperm[1];
        puh[0] = A_hi32[ta * 128 + j]; pul[0] = A_lo32[ta * 128 + j];
        puh[1] = A_hi32[tb * 128 + j]; pul[1] = A_lo32[tb * 128 + j];
    }
#pragma unroll
    for (int i = 0; i < 32; ++i) {
        uint32_t cuh = puh[i & 1], cul = pul[i & 1];
        if (i + 2 < 32) {
            int tn = sperm[i + 2];
            puh[i & 1] = A_hi32[tn * 128 + j];
            pul[i & 1] = A_lo32[tn * 128 + j];
        }
        int code = scode[i];
        if (code != cur) {                       // wave-uniform branch
            atomicAdd(&es[cur * 256 + 2 * j],     s0);
            atomicAdd(&es[cur * 256 + 2 * j + 1], s1);
            s0 = 0.f; s1 = 0.f; cur = code;
        }
        s0 += unpack_sum(cuh, cul, 0);
        s1 += unpack_sum(cuh, cul, 1);
    }
    atomicAdd(&es[cur * 256 + 2 * j],     s0);
    atomicAdd(&es[cur * 256 + 2 * j + 1], s1);
}

// ---- EMA finalize for embed_avg / embed ----
__global__ void finalize_embed(const float* __restrict__ embed_avg,
                               const float* __restrict__ es,
                               const float* __restrict__ csnorm,
                               float* __restrict__ out_embed,
                               float* __restrict__ out_nea)
{
    int idx = blockIdx.x * 256 + threadIdx.x;
    int k = idx >> 8;
    float nea = embed_avg[idx] * DECAY + OMDECAY * es[idx];
    out_nea[idx] = nea;
    out_embed[idx] = nea / csnorm[k];
}

extern "C" void kernel_launch(void* const* d_in, const int* in_sizes, int n_in,
                              void* d_out, int out_size, void* d_ws, size_t ws_size,
                              hipStream_t stream) {
    const float* z            = (const float*)d_in[0];
    const float* embed        = (const float*)d_in[1];
    const float* cluster_size = (const float*)d_in[2];
    const float* embed_avg    = (const float*)d_in[3];
    float* out = (float*)d_out;
    uint32_t* ws32 = (uint32_t*)d_ws;

    uint32_t* B_hi32 = ws32 + 0;
    uint32_t* B_lo32 = ws32 + 131072;
    uint32_t* A_hi32 = ws32 + 262144;
    uint32_t* A_lo32 = ws32 + 4456448;
    int* perm        = (int*)(ws32 + 8650752);
    int* offsets     = (int*)(ws32 + 8683520);
    int* cursor      = (int*)(ws32 + 8684544);
    float* cs        = (float*)(ws32 + 8912896);
    float* loss_sum  = (float*)(ws32 + 8913920);
    float* enorm     = (float*)(ws32 + 8914944);
    float* csnorm    = (float*)(ws32 + 8915968);
    float* es        = (float*)(ws32 + 0);        // reuses B_hi/B_lo after vq_mfma

    hipMemsetAsync((void*)cs, 0, (size_t)2048 * 4, stream);

    split_embed<<<1024, 256, 0, stream>>>(embed, (unsigned short*)B_hi32, (unsigned short*)B_lo32);
    split_z<<<1024, 256, 0, stream>>>(z, A_hi32, A_lo32);
    compute_enorm<<<256, 256, 0, stream>>>(embed, enorm);
    vq_mfma<<<512, 256, 0, stream>>>(z, embed, A_hi32, A_lo32, B_hi32, B_lo32, enorm,
                                     out, out + 8388608, cs, loss_sum);
    vq_finalize_small<<<1, 1024, 0, stream>>>(cluster_size, cs, loss_sum,
                                              out + 8421376, out + 8683521, csnorm,
                                              offsets, cursor);
    scatter_perm<<<128, 256, 0, stream>>>(out + 8388608, cursor, perm);
    // B dead now; zero its region and reuse as es
    hipMemsetAsync((void*)es, 0, (size_t)262144 * 4, stream);
    es_sum<<<1024, 128, 0, stream>>>(A_hi32, A_lo32, perm, out + 8388608, es);
    finalize_embed<<<1024, 256, 0, stream>>>(embed_avg, es, csnorm,
                                             out + 8421377, out + 8684545);
}

// Round 5
// 278.943 us; speedup vs baseline: 6.4991x; 1.0454x over previous
//
#include <hip/hip_runtime.h>
#include <stdint.h>

#define DECAY 0.99f
#define OMDECAY 0.01f
#define EPSV 1e-5f

// Problem: z (32,256,32,32) fp32; tokens N=32768, D=256, K=1024 codes.
// out (floats): zq[0,8388608) idx[8388608,8421376) loss[8421376]
//               new_embed[8421377,..) new_cs[8683521,..) new_ea[8684545,..)
// ws (dwords):
//   B_hi32   0        (131072)   1024x256 f16 packed 2/dword   } es (262144 fp32)
//   B_lo32   131072   (131072)                                 } reused after vq_mfma
//   A_hi32   262144   (4194304)  32768x256 f16, token-major
//   A_lo32   4456448  (4194304)
//   perm     8650752  (32768)    int, tokens sorted by code
//   offsets  8683520  (1024)     int, segment starts
//   cursor   8684544  (1024)     int, atomic cursors
//   cs       8912896  (1024)     fp32 histogram
//   loss     8913920  (1024, 1 used)
//   enorm    8914944  (1024)
//   csnorm   8915968  (1024)

typedef _Float16 half8 __attribute__((ext_vector_type(8)));
typedef float floatx4 __attribute__((ext_vector_type(4)));

typedef __attribute__((address_space(1))) const uint32_t gu32;
typedef __attribute__((address_space(3))) uint32_t lu32;

__device__ __forceinline__ void gld16(uint32_t* l, const uint32_t* g) {
    __builtin_amdgcn_global_load_lds((gu32*)g, (lu32*)l, 16, 0, 0);
}

__device__ __forceinline__ uint32_t pack_hl(float v) {
    _Float16 h = (_Float16)v;
    _Float16 lo = (_Float16)(v - (float)h);
    return (uint32_t)__builtin_bit_cast(unsigned short, h) |
           ((uint32_t)__builtin_bit_cast(unsigned short, lo) << 16);
}

// ---- prep: split embed + enorm + zero cs/loss, one launch ----
// 1024 blocks x 256 threads; block = one code row.
__global__ void prep_embed(const float* __restrict__ embed,
                           unsigned short* __restrict__ B_hi16,
                           unsigned short* __restrict__ B_lo16,
                           float* __restrict__ enorm,
                           float* __restrict__ cs /* + loss contiguous */) {
    __shared__ float ws4[4];
    const int k = blockIdx.x;
    const int tid = threadIdx.x;
    const int lane = tid & 63;
    const int wv = tid >> 6;
    int idx = k * 256 + tid;
    float v = embed[idx];
    _Float16 h = (_Float16)v;
    _Float16 lo = (_Float16)(v - (float)h);
    B_hi16[idx] = __builtin_bit_cast(unsigned short, h);
    B_lo16[idx] = __builtin_bit_cast(unsigned short, lo);
    float s = v * v;
    for (int off = 32; off > 0; off >>= 1) s += __shfl_down(s, off);
    if (lane == 0) ws4[wv] = s;
    __syncthreads();
    if (tid == 0) enorm[k] = ws4[0] + ws4[1] + ws4[2] + ws4[3];
    if (k == 0) {
        for (int i = tid; i < 2048; i += 256) cs[i] = 0.f;   // cs + loss_sum
    }
}

// ---- prep: z (b,d,h,w) -> token-major f16 hi/lo A[t][d], all 64 lanes ----
__global__ void split_z(const float* __restrict__ z,
                        uint32_t* __restrict__ A_hi32,
                        uint32_t* __restrict__ A_lo32) {
    __shared__ uint32_t sp[32 * 258];
    const int lane = threadIdx.x & 63;
    const int wv   = threadIdx.x >> 6;
    const int t0   = blockIdx.x * 32;
    const int b    = t0 >> 10;
    const int hw0  = t0 & 1023;
    const int l32  = lane & 31;
    const int dh   = lane >> 5;

    for (int dp = wv; dp < 128; dp += 4) {
        int dd = dp * 2 + dh;
        float v = z[b * 262144 + dd * 1024 + hw0 + l32];
        sp[l32 * 258 + dd] = pack_hl(v);
    }
    __syncthreads();
    for (int r = wv; r < 32; r += 4) {
#pragma unroll
        for (int h2 = 0; h2 < 2; ++h2) {
            int dpair = h2 * 64 + lane;
            uint32_t u0 = sp[r * 258 + 2 * dpair];
            uint32_t u1 = sp[r * 258 + 2 * dpair + 1];
            A_hi32[(t0 + r) * 128 + dpair] = (u0 & 0xffffu) | (u1 << 16);
            A_lo32[(t0 + r) * 128 + dpair] = (u0 >> 16) | (u1 & 0xffff0000u);
        }
    }
}

// ---- main: MFMA distance GEMM + fused argmin + zq/loss epilogue ----
// 256 blocks x 256 thr. Block = 128 tokens x all 1024 codes.
// Per nc (256 codes): wave w covers codes nc*256 + w*64 + j*16 + c16;
// per-wave tile 128 tok x 64 codes = 8x4 MFMA tiles, acc in AGPRs.
__global__ __launch_bounds__(256, 1) void vq_mfma(
    const float* __restrict__ z,
    const float* __restrict__ embed,
    const uint32_t* __restrict__ A_hi32,
    const uint32_t* __restrict__ A_lo32,
    const uint32_t* __restrict__ B_hi32,
    const uint32_t* __restrict__ B_lo32,
    const float* __restrict__ enorm,
    float* __restrict__ out_zq,
    float* __restrict__ out_idx,
    float* __restrict__ cs,
    float* __restrict__ loss_sum)
{
    __shared__ __align__(16) _Float16 AsH[128 * 32];   // 8 KB
    __shared__ __align__(16) _Float16 AsL[128 * 32];   // 8 KB
    __shared__ __align__(16) _Float16 BsH[256 * 32];   // 16 KB
    __shared__ __align__(16) _Float16 BsL[256 * 32];   // 16 KB
    __shared__ float smv[512];
    __shared__ int   smi[512];
    __shared__ int   sidx[128];

    const int lane = threadIdx.x & 63;
    const int w    = threadIdx.x >> 6;
    const int q    = lane >> 4;
    const int c16  = lane & 15;
    const int t0   = blockIdx.x * 128;
    const int lane4 = lane >> 2;          // staging: row within 16-row segment
    const int dd8   = (lane & 3) * 8;     // staging: d offset (8 halves)

    // per-slot best across ALL nc, slot = i*4 + r  (token = i*16 + q*4 + r)
    float bestv[32];
    int   besti[32];
#pragma unroll
    for (int s = 0; s < 32; ++s) { bestv[s] = 3.4e38f; besti[s] = 0; }

    for (int nc = 0; nc < 4; ++nc) {
        floatx4 acc[8][4];
#pragma unroll
        for (int i = 0; i < 8; ++i)
#pragma unroll
            for (int j = 0; j < 4; ++j)
                acc[i][j] = (floatx4){0.f, 0.f, 0.f, 0.f};

        for (int dc = 0; dc < 8; ++dc) {
            const int d0 = dc * 32;
            __syncthreads();   // prior frag reads done before overwrite
            // stage 48 KB: A hi/lo (8+8 segs of 1 KB), B hi/lo (16+16 segs)
            for (int s = w; s < 48; s += 4) {
                if (s < 16) {
                    int ss = s & 7;
                    const uint32_t* base = (s < 8) ? A_hi32 : A_lo32;
                    uint32_t* dst = (uint32_t*)((s < 8) ? AsH : AsL) + ss * 256;
                    int tok = ss * 16 + lane4;
                    gld16(dst, base + (t0 + tok) * 128 + ((d0 + dd8) >> 1));
                } else {
                    int sb = s - 16;
                    int ss = sb & 15;
                    const uint32_t* base = (sb < 16) ? B_hi32 : B_lo32;
                    uint32_t* dst = (uint32_t*)((sb < 16) ? BsH : BsL) + ss * 256;
                    int code = nc * 256 + ss * 16 + lane4;
                    gld16(dst, base + code * 128 + ((d0 + dd8) >> 1));
                }
            }
            __syncthreads();   // drains vmcnt(0): staged data visible

            half8 bH[4], bL[4];
#pragma unroll
            for (int j = 0; j < 4; ++j) {
                int off = (w * 64 + j * 16 + c16) * 32 + q * 8;
                bH[j] = *(const half8*)(BsH + off);
                bL[j] = *(const half8*)(BsL + off);
            }
#pragma unroll
            for (int i = 0; i < 8; ++i) {
                int off = (i * 16 + c16) * 32 + q * 8;
                half8 aH = *(const half8*)(AsH + off);
                half8 aL = *(const half8*)(AsL + off);
#pragma unroll
                for (int j = 0; j < 4; ++j) {
                    acc[i][j] = __builtin_amdgcn_mfma_f32_16x16x32_f16(aH, bH[j], acc[i][j], 0, 0, 0);
                    acc[i][j] = __builtin_amdgcn_mfma_f32_16x16x32_f16(aH, bL[j], acc[i][j], 0, 0, 0);
                    acc[i][j] = __builtin_amdgcn_mfma_f32_16x16x32_f16(aL, bH[j], acc[i][j], 0, 0, 0);
                }
            }
        }

        // score = ||e||^2 - 2*dot ; codes ascend with nc -> strict < keeps lowest
#pragma unroll
        for (int j = 0; j < 4; ++j) {
            int code = nc * 256 + w * 64 + j * 16 + c16;
            float en = enorm[code];
#pragma unroll
            for (int i = 0; i < 8; ++i)
#pragma unroll
                for (int r = 0; r < 4; ++r) {
                    float sc = en - 2.0f * acc[i][j][r];
                    int slot = i * 4 + r;
                    if (sc < bestv[slot] || (sc == bestv[slot] && code < besti[slot])) {
                        bestv[slot] = sc; besti[slot] = code;
                    }
                }
        }
    }

    // single butterfly argmin across the 16 c16-lanes sharing each token
#pragma unroll
    for (int slot = 0; slot < 32; ++slot) {
        float v = bestv[slot]; int bi = besti[slot];
#pragma unroll
        for (int m = 1; m < 16; m <<= 1) {
            float ov = __shfl_xor(v, m);
            int   oi = __shfl_xor(bi, m);
            if (ov < v || (ov == v && oi < bi)) { v = ov; bi = oi; }
        }
        bestv[slot] = v; besti[slot] = bi;
    }
    if (c16 == 0) {
#pragma unroll
        for (int i = 0; i < 8; ++i)
#pragma unroll
            for (int r = 0; r < 4; ++r) {
                int ltok = i * 16 + q * 4 + r;
                smv[w * 128 + ltok] = bestv[i * 4 + r];
                smi[w * 128 + ltok] = besti[i * 4 + r];
            }
    }
    __syncthreads();

    // cross-wave merge (waves cover disjoint code ranges; tie -> lowest code)
    if (threadIdx.x < 128) {
        float bv = smv[threadIdx.x];
        int   bi = smi[threadIdx.x];
#pragma unroll
        for (int ww = 1; ww < 4; ++ww) {
            float v  = smv[ww * 128 + threadIdx.x];
            int   ii = smi[ww * 128 + threadIdx.x];
            if (v < bv || (v == bv && ii < bi)) { bv = v; bi = ii; }
        }
        sidx[threadIdx.x] = bi;
        out_idx[t0 + threadIdx.x] = (float)bi;
        atomicAdd(&cs[bi], 1.0f);
    }
    __syncthreads();

    // epilogue: z_q store + loss (two tokens per lane)
    const int b_idx = t0 >> 10;
    const int hw0   = t0 & 1023;
    const int zbase = b_idx * 262144 + hw0;
    const int ka = sidx[lane];
    const int kb = sidx[lane + 64];
    float lsum = 0.f;
    for (int d = w; d < 256; d += 4) {
        float zv0 = z[zbase + d * 1024 + lane];
        float zv1 = z[zbase + d * 1024 + lane + 64];
        float e0 = embed[ka * 256 + d];
        float e1 = embed[kb * 256 + d];
        out_zq[zbase + d * 1024 + lane]      = zv0 + (e0 - zv0);
        out_zq[zbase + d * 1024 + lane + 64] = zv1 + (e1 - zv1);
        float d0f = zv0 - e0, d1f = zv1 - e1;
        lsum += d0f * d0f + d1f * d1f;
    }
    for (int off = 32; off > 0; off >>= 1) lsum += __shfl_down(lsum, off);
    if (lane == 0) atomicAdd(loss_sum, lsum);
}

// ---- finalize: loss, new_cluster, csnorm, prefix-scan (wave shuffles) ----
__global__ void vq_finalize_small(const float* __restrict__ cluster_size,
                                  const float* __restrict__ cs,
                                  const float* __restrict__ loss_sum,
                                  float* __restrict__ out_loss,
                                  float* __restrict__ out_ncs,
                                  float* __restrict__ csnorm,
                                  int* __restrict__ offsets,
                                  int* __restrict__ cursor)
{
    __shared__ float wsum[16];
    __shared__ float wncs[16];
    __shared__ float stot[1];
    const int k = threadIdx.x;          // 0..1023
    const int lane = k & 63;
    const int wv = k >> 6;              // 16 waves
    float cnt = cs[k];
    float ncs = cluster_size[k] * DECAY + OMDECAY * cnt;
    out_ncs[k] = ncs;
    // wave-inclusive scan of counts
    float sc = cnt;
#pragma unroll
    for (int d = 1; d < 64; d <<= 1) {
        float up = __shfl_up(sc, d);
        if (lane >= d) sc += up;
    }
    if (lane == 63) wsum[wv] = sc;
    // wave sum of ncs
    float ns = ncs;
    for (int off = 32; off > 0; off >>= 1) ns += __shfl_down(ns, off);
    if (lane == 0) wncs[wv] = ns;
    __syncthreads();
    if (wv == 0) {
        float v = (lane < 16) ? wsum[lane] : 0.f;
#pragma unroll
        for (int d = 1; d < 16; d <<= 1) {
            float up = __shfl_up(v, d);
            if (lane >= d) v += up;
        }
        if (lane < 16) wsum[lane] = v;       // inclusive scan of wave totals
    } else if (wv == 1) {
        float t = (lane < 16) ? wncs[lane] : 0.f;
        for (int off = 32; off > 0; off >>= 1) t += __shfl_down(t, off);
        if (lane == 0) stot[0] = t;
    }
    __syncthreads();
    float incl = sc + (wv ? wsum[wv - 1] : 0.f);
    int excl = __float2int_rn(incl - cnt);
    offsets[k] = excl;
    cursor[k]  = excl;
    float n = stot[0];
    csnorm[k] = (ncs + EPSV) / (n + 1024.0f * EPSV) * n;
    if (k == 0) out_loss[0] = loss_sum[0] / 8388608.0f;
}

// ---- counting-sort scatter + es zeroing (absorbs the memset) ----
__global__ void scatter_perm(const float* __restrict__ out_idx,
                             int* __restrict__ cursor,
                             int* __restrict__ perm,
                             float* __restrict__ es)
{
    int t = blockIdx.x * 256 + threadIdx.x;   // 0..32767
#pragma unroll
    for (int i = 0; i < 8; ++i) es[t + i * 32768] = 0.f;
    int code = (int)out_idx[t];
    int pos = atomicAdd(&cursor[code], 1);
    perm[pos] = t;
}

// ---- chunked segmented sum over the SORTED token list ----
// 1024 blocks x 256 threads; block = 32 perm entries.
// tid<128 -> hi array, tid>=128 -> lo array; both atomically add partials.
__global__ void es_sum(const uint32_t* __restrict__ A_hi32,
                       const uint32_t* __restrict__ A_lo32,
                       const int* __restrict__ perm,
                       const float* __restrict__ out_idx,
                       float* __restrict__ es)
{
    __shared__ int sperm[32];
    __shared__ int scode[32];
    const int base = blockIdx.x * 32;
    const int tid = threadIdx.x;
    const int j = tid & 127;                  // dword (dims 2j, 2j+1)
    const uint32_t* __restrict__ A = (tid >> 7) ? A_lo32 : A_hi32;
    if (tid < 32) {
        int t = perm[base + tid];
        sperm[tid] = t;
        scode[tid] = (int)out_idx[t];
    }
    __syncthreads();

    float s0 = 0.f, s1 = 0.f;
    int cur = scode[0];
    uint32_t pu[2];
    pu[0] = A[sperm[0] * 128 + j];
    pu[1] = A[sperm[1] * 128 + j];
#pragma unroll
    for (int i = 0; i < 32; ++i) {
        uint32_t u = pu[i & 1];
        if (i + 2 < 32) pu[i & 1] = A[sperm[i + 2] * 128 + j];
        int code = scode[i];
        if (code != cur) {                    // wave-uniform branch
            atomicAdd(&es[cur * 256 + 2 * j],     s0);
            atomicAdd(&es[cur * 256 + 2 * j + 1], s1);
            s0 = 0.f; s1 = 0.f; cur = code;
        }
        s0 += (float)__builtin_bit_cast(_Float16, (unsigned short)(u & 0xffffu));
        s1 += (float)__builtin_bit_cast(_Float16, (unsigned short)(u >> 16));
    }
    atomicAdd(&es[cur * 256 + 2 * j],     s0);
    atomicAdd(&es[cur * 256 + 2 * j + 1], s1);
}

// ---- EMA finalize for embed_avg / embed ----
__global__ void finalize_embed(const float* __restrict__ embed_avg,
                               const float* __restrict__ es,
                               const float* __restrict__ csnorm,
                               float* __restrict__ out_embed,
                               float* __restrict__ out_nea)
{
    int idx = blockIdx.x * 256 + threadIdx.x;
    int k = idx >> 8;
    float nea = embed_avg[idx] * DECAY + OMDECAY * es[idx];
    out_nea[idx] = nea;
    out_embed[idx] = nea / csnorm[k];
}

extern "C" void kernel_launch(void* const* d_in, const int* in_sizes, int n_in,
                              void* d_out, int out_size, void* d_ws, size_t ws_size,
                              hipStream_t stream) {
    const float* z            = (const float*)d_in[0];
    const float* embed        = (const float*)d_in[1];
    const float* cluster_size = (const float*)d_in[2];
    const float* embed_avg    = (const float*)d_in[3];
    float* out = (float*)d_out;
    uint32_t* ws32 = (uint32_t*)d_ws;

    uint32_t* B_hi32 = ws32 + 0;
    uint32_t* B_lo32 = ws32 + 131072;
    uint32_t* A_hi32 = ws32 + 262144;
    uint32_t* A_lo32 = ws32 + 4456448;
    int* perm        = (int*)(ws32 + 8650752);
    int* offsets     = (int*)(ws32 + 8683520);
    int* cursor      = (int*)(ws32 + 8684544);
    float* cs        = (float*)(ws32 + 8912896);
    float* loss_sum  = (float*)(ws32 + 8913920);
    float* enorm     = (float*)(ws32 + 8914944);
    float* csnorm    = (float*)(ws32 + 8915968);
    float* es        = (float*)(ws32 + 0);        // reuses B_hi/B_lo after vq_mfma

    prep_embed<<<1024, 256, 0, stream>>>(embed, (unsigned short*)B_hi32,
                                         (unsigned short*)B_lo32, enorm, cs);
    split_z<<<1024, 256, 0, stream>>>(z, A_hi32, A_lo32);
    vq_mfma<<<256, 256, 0, stream>>>(z, embed, A_hi32, A_lo32, B_hi32, B_lo32, enorm,
                                     out, out + 8388608, cs, loss_sum);
    vq_finalize_small<<<1, 1024, 0, stream>>>(cluster_size, cs, loss_sum,
                                              out + 8421376, out + 8683521, csnorm,
                                              offsets, cursor);
    scatter_perm<<<128, 256, 0, stream>>>(out + 8388608, cursor, perm, es);
    es_sum<<<1024, 256, 0, stream>>>(A_hi32, A_lo32, perm, out + 8388608, es);
    finalize_embed<<<1024, 256, 0, stream>>>(embed_avg, es, csnorm,
                                             out + 8421377, out + 8684545);
}

// Round 6
// 264.396 us; speedup vs baseline: 6.8567x; 1.0550x over previous
//
#include <hip/hip_runtime.h>
#include <stdint.h>

#define DECAY 0.99f
#define OMDECAY 0.01f
#define EPSV 1e-5f

// Problem: z (32,256,32,32) fp32; tokens N=32768, D=256, K=1024 codes.
// out (floats): zq[0,8388608) idx[8388608,8421376) loss[8421376]
//               new_embed[8421377,..) new_cs[8683521,..) new_ea[8684545,..)
//   best64 scratch overlays new_embed region at out+8421378 (65536 dwords),
//   dead before finalize_embed overwrites it.
// ws (dwords):
//   B_hi32   0        (131072)   1024x256 f16 packed 2/dword   } es (262144 fp32)
//   B_lo32   131072   (131072)                                 } reused after vq_mfma
//   A_hi32   262144   (4194304)  32768x256 f16, token-major
//   A_lo32   4456448  (4194304)
//   perm     8650752  (32768)    int, tokens sorted by code
//   offsets  8683520  (1024)     int, segment starts
//   cursor   8684544  (1024)     int, atomic cursors
//   cs       8912896  (1024)     fp32 histogram
//   loss     8913920  (1024, 1 used)
//   enorm    8914944  (1024)
//   csnorm   8915968  (1024)

typedef _Float16 half8 __attribute__((ext_vector_type(8)));
typedef float floatx4 __attribute__((ext_vector_type(4)));

typedef __attribute__((address_space(1))) const uint32_t gu32;
typedef __attribute__((address_space(3))) uint32_t lu32;

__device__ __forceinline__ void gld16(uint32_t* l, const uint32_t* g) {
    __builtin_amdgcn_global_load_lds((gu32*)g, (lu32*)l, 16, 0, 0);
}

__device__ __forceinline__ uint32_t pack_hl(float v) {
    _Float16 h = (_Float16)v;
    _Float16 lo = (_Float16)(v - (float)h);
    return (uint32_t)__builtin_bit_cast(unsigned short, h) |
           ((uint32_t)__builtin_bit_cast(unsigned short, lo) << 16);
}

// monotone float -> uint32 (ascending order preserved)
__device__ __forceinline__ unsigned int encf(float s) {
    unsigned int b = __builtin_bit_cast(unsigned int, s);
    return (b & 0x80000000u) ? ~b : (b | 0x80000000u);
}

// ---- prep: split embed + enorm + zero cs/loss + init best64 keys ----
__global__ void prep_embed(const float* __restrict__ embed,
                           unsigned short* __restrict__ B_hi16,
                           unsigned short* __restrict__ B_lo16,
                           float* __restrict__ enorm,
                           float* __restrict__ cs /* + loss contiguous */,
                           uint32_t* __restrict__ b64i) {
    __shared__ float ws4[4];
    const int k = blockIdx.x;
    const int tid = threadIdx.x;
    const int lane = tid & 63;
    const int wv = tid >> 6;
    int idx = k * 256 + tid;
    float v = embed[idx];
    _Float16 h = (_Float16)v;
    _Float16 lo = (_Float16)(v - (float)h);
    B_hi16[idx] = __builtin_bit_cast(unsigned short, h);
    B_lo16[idx] = __builtin_bit_cast(unsigned short, lo);
    float s = v * v;
    for (int off = 32; off > 0; off >>= 1) s += __shfl_down(s, off);
    if (lane == 0) ws4[wv] = s;
    __syncthreads();
    if (tid == 0) enorm[k] = ws4[0] + ws4[1] + ws4[2] + ws4[3];
    if (k < 256) b64i[k * 256 + tid] = 0xFFFFFFFFu;   // best64 = +inf keys
    if (k == 0) {
        for (int i = tid; i < 2048; i += 256) cs[i] = 0.f;   // cs + loss_sum
    }
}

// ---- prep: z (b,d,h,w) -> token-major f16 hi/lo A[t][d] ----
__global__ void split_z(const float* __restrict__ z,
                        uint32_t* __restrict__ A_hi32,
                        uint32_t* __restrict__ A_lo32) {
    __shared__ uint32_t sp[32 * 258];
    const int lane = threadIdx.x & 63;
    const int wv   = threadIdx.x >> 6;
    const int t0   = blockIdx.x * 32;
    const int b    = t0 >> 10;
    const int hw0  = t0 & 1023;
    const int l32  = lane & 31;
    const int dh   = lane >> 5;

    for (int dp = wv; dp < 128; dp += 4) {
        int dd = dp * 2 + dh;
        float v = z[b * 262144 + dd * 1024 + hw0 + l32];
        sp[l32 * 258 + dd] = pack_hl(v);
    }
    __syncthreads();
    for (int r = wv; r < 32; r += 4) {
#pragma unroll
        for (int h2 = 0; h2 < 2; ++h2) {
            int dpair = h2 * 64 + lane;
            uint32_t u0 = sp[r * 258 + 2 * dpair];
            uint32_t u1 = sp[r * 258 + 2 * dpair + 1];
            A_hi32[(t0 + r) * 128 + dpair] = (u0 & 0xffffu) | (u1 << 16);
            A_lo32[(t0 + r) * 128 + dpair] = (u0 >> 16) | (u1 & 0xffff0000u);
        }
    }
}

// ---- main: MFMA distance GEMM + argmin via packed atomicMin ----
// 512 blocks = 256 token-groups(128 tok) x 2 code-halves (512 codes).
// Per nc (256 codes): wave w covers codes cb + nc*256 + w*64 + j*16 + c16.
__global__ __launch_bounds__(256, 2) void vq_mfma(
    const uint32_t* __restrict__ A_hi32,
    const uint32_t* __restrict__ A_lo32,
    const uint32_t* __restrict__ B_hi32,
    const uint32_t* __restrict__ B_lo32,
    const float* __restrict__ enorm,
    unsigned long long* __restrict__ best64)
{
    __shared__ __align__(16) _Float16 AsH[128 * 32];   // 8 KB
    __shared__ __align__(16) _Float16 AsL[128 * 32];   // 8 KB
    __shared__ __align__(16) _Float16 BsH[256 * 32];   // 16 KB
    __shared__ __align__(16) _Float16 BsL[256 * 32];   // 16 KB

    const int lane = threadIdx.x & 63;
    const int w    = threadIdx.x >> 6;
    const int q    = lane >> 4;
    const int c16  = lane & 15;
    const int t0   = (blockIdx.x >> 1) * 128;   // token base
    const int cb   = (blockIdx.x & 1) * 512;    // code-half base
    const int lane4 = lane >> 2;
    const int dd8   = (lane & 3) * 8;

    for (int nc = 0; nc < 2; ++nc) {
        floatx4 acc[8][4];
#pragma unroll
        for (int i = 0; i < 8; ++i)
#pragma unroll
            for (int j = 0; j < 4; ++j)
                acc[i][j] = (floatx4){0.f, 0.f, 0.f, 0.f};

        for (int dc = 0; dc < 8; ++dc) {
            const int d0 = dc * 32;
            __syncthreads();   // prior frag reads done before overwrite
            // stage 48 KB: A hi/lo (8+8 segs of 1 KB), B hi/lo (16+16 segs)
            for (int s = w; s < 48; s += 4) {
                if (s < 16) {
                    int ss = s & 7;
                    const uint32_t* base = (s < 8) ? A_hi32 : A_lo32;
                    uint32_t* dst = (uint32_t*)((s < 8) ? AsH : AsL) + ss * 256;
                    int tok = ss * 16 + lane4;
                    gld16(dst, base + (t0 + tok) * 128 + ((d0 + dd8) >> 1));
                } else {
                    int sb = s - 16;
                    int ss = sb & 15;
                    const uint32_t* base = (sb < 16) ? B_hi32 : B_lo32;
                    uint32_t* dst = (uint32_t*)((sb < 16) ? BsH : BsL) + ss * 256;
                    int code = cb + nc * 256 + ss * 16 + lane4;
                    gld16(dst, base + code * 128 + ((d0 + dd8) >> 1));
                }
            }
            __syncthreads();   // drains vmcnt(0): staged data visible

            half8 bH[4], bL[4];
#pragma unroll
            for (int j = 0; j < 4; ++j) {
                int off = (w * 64 + j * 16 + c16) * 32 + q * 8;
                bH[j] = *(const half8*)(BsH + off);
                bL[j] = *(const half8*)(BsL + off);
            }
#pragma unroll
            for (int i = 0; i < 8; ++i) {
                int off = (i * 16 + c16) * 32 + q * 8;
                half8 aH = *(const half8*)(AsH + off);
                half8 aL = *(const half8*)(AsL + off);
#pragma unroll
                for (int j = 0; j < 4; ++j) {
                    acc[i][j] = __builtin_amdgcn_mfma_f32_16x16x32_f16(aH, bH[j], acc[i][j], 0, 0, 0);
                    acc[i][j] = __builtin_amdgcn_mfma_f32_16x16x32_f16(aH, bL[j], acc[i][j], 0, 0, 0);
                    acc[i][j] = __builtin_amdgcn_mfma_f32_16x16x32_f16(aL, bH[j], acc[i][j], 0, 0, 0);
                }
            }
        }

        // score = ||e||^2 - 2*dot ; per-nc best, tie -> lowest code
        float bestv[32];
        int   besti[32];
#pragma unroll
        for (int s = 0; s < 32; ++s) { bestv[s] = 3.4e38f; besti[s] = 0; }
#pragma unroll
        for (int j = 0; j < 4; ++j) {
            int code = cb + nc * 256 + w * 64 + j * 16 + c16;
            float en = enorm[code];
#pragma unroll
            for (int i = 0; i < 8; ++i)
#pragma unroll
                for (int r = 0; r < 4; ++r) {
                    float sc = en - 2.0f * acc[i][j][r];
                    int slot = i * 4 + r;
                    if (sc < bestv[slot] || (sc == bestv[slot] && code < besti[slot])) {
                        bestv[slot] = sc; besti[slot] = code;
                    }
                }
        }
        // butterfly argmin across the 16 c16-lanes sharing each token
#pragma unroll
        for (int slot = 0; slot < 32; ++slot) {
            float v = bestv[slot]; int bi = besti[slot];
#pragma unroll
            for (int m = 1; m < 16; m <<= 1) {
                float ov = __shfl_xor(v, m);
                int   oi = __shfl_xor(bi, m);
                if (ov < v || (ov == v && oi < bi)) { v = ov; bi = oi; }
            }
            bestv[slot] = v; besti[slot] = bi;
        }
        // distributed packed atomicMin: lane c16 owns slots c16, c16+16
#pragma unroll
        for (int slot = 0; slot < 32; ++slot) {
            if (c16 == (slot & 15)) {
                int tok = (slot >> 2) * 16 + q * 4 + (slot & 3);
                unsigned long long key =
                    ((unsigned long long)encf(bestv[slot]) << 32) |
                    (unsigned int)besti[slot];
                atomicMin(&best64[t0 + tok], key);
            }
        }
    }
}

// ---- merge: decode best64 -> idx/cs, write zq + loss ----
__global__ __launch_bounds__(256) void merge_zq(
    const unsigned long long* __restrict__ best64,
    const float* __restrict__ z,
    const float* __restrict__ embed,
    float* __restrict__ out_zq,
    float* __restrict__ out_idx,
    float* __restrict__ cs,
    float* __restrict__ loss_sum)
{
    __shared__ int sidx[128];
    const int tid = threadIdx.x;
    const int lane = tid & 63;
    const int w = tid >> 6;
    const int t0 = blockIdx.x * 128;

    if (tid < 128) {
        int bi = (int)(unsigned int)(best64[t0 + tid] & 0xffffffffULL);
        sidx[tid] = bi;
        out_idx[t0 + tid] = (float)bi;
        atomicAdd(&cs[bi], 1.0f);
    }
    __syncthreads();

    const int b_idx = t0 >> 10;
    const int hw0   = t0 & 1023;
    const int zbase = b_idx * 262144 + hw0;
    const int ka = sidx[lane];
    const int kb = sidx[lane + 64];
    float lsum = 0.f;
    for (int d = w; d < 256; d += 4) {
        float zv0 = z[zbase + d * 1024 + lane];
        float zv1 = z[zbase + d * 1024 + lane + 64];
        float e0 = embed[ka * 256 + d];
        float e1 = embed[kb * 256 + d];
        out_zq[zbase + d * 1024 + lane]      = zv0 + (e0 - zv0);
        out_zq[zbase + d * 1024 + lane + 64] = zv1 + (e1 - zv1);
        float d0f = zv0 - e0, d1f = zv1 - e1;
        lsum += d0f * d0f + d1f * d1f;
    }
    for (int off = 32; off > 0; off >>= 1) lsum += __shfl_down(lsum, off);
    if (lane == 0) atomicAdd(loss_sum, lsum);
}

// ---- finalize: loss, new_cluster, csnorm, prefix-scan (wave shuffles) ----
__global__ void vq_finalize_small(const float* __restrict__ cluster_size,
                                  const float* __restrict__ cs,
                                  const float* __restrict__ loss_sum,
                                  float* __restrict__ out_loss,
                                  float* __restrict__ out_ncs,
                                  float* __restrict__ csnorm,
                                  int* __restrict__ offsets,
                                  int* __restrict__ cursor)
{
    __shared__ float wsum[16];
    __shared__ float wncs[16];
    __shared__ float stot[1];
    const int k = threadIdx.x;
    const int lane = k & 63;
    const int wv = k >> 6;
    float cnt = cs[k];
    float ncs = cluster_size[k] * DECAY + OMDECAY * cnt;
    out_ncs[k] = ncs;
    float sc = cnt;
#pragma unroll
    for (int d = 1; d < 64; d <<= 1) {
        float up = __shfl_up(sc, d);
        if (lane >= d) sc += up;
    }
    if (lane == 63) wsum[wv] = sc;
    float ns = ncs;
    for (int off = 32; off > 0; off >>= 1) ns += __shfl_down(ns, off);
    if (lane == 0) wncs[wv] = ns;
    __syncthreads();
    if (wv == 0) {
        float v = (lane < 16) ? wsum[lane] : 0.f;
#pragma unroll
        for (int d = 1; d < 16; d <<= 1) {
            float up = __shfl_up(v, d);
            if (lane >= d) v += up;
        }
        if (lane < 16) wsum[lane] = v;
    } else if (wv == 1) {
        float t = (lane < 16) ? wncs[lane] : 0.f;
        for (int off = 32; off > 0; off >>= 1) t += __shfl_down(t, off);
        if (lane == 0) stot[0] = t;
    }
    __syncthreads();
    float incl = sc + (wv ? wsum[wv - 1] : 0.f);
    int excl = __float2int_rn(incl - cnt);
    offsets[k] = excl;
    cursor[k]  = excl;
    float n = stot[0];
    csnorm[k] = (ncs + EPSV) / (n + 1024.0f * EPSV) * n;
    if (k == 0) out_loss[0] = loss_sum[0] / 8388608.0f;
}

// ---- counting-sort scatter + es zeroing ----
__global__ void scatter_perm(const float* __restrict__ out_idx,
                             int* __restrict__ cursor,
                             int* __restrict__ perm,
                             float* __restrict__ es)
{
    int t = blockIdx.x * 256 + threadIdx.x;
#pragma unroll
    for (int i = 0; i < 8; ++i) es[t + i * 32768] = 0.f;
    int code = (int)out_idx[t];
    int pos = atomicAdd(&cursor[code], 1);
    perm[pos] = t;
}

// ---- chunked segmented sum over the SORTED token list ----
__global__ void es_sum(const uint32_t* __restrict__ A_hi32,
                       const uint32_t* __restrict__ A_lo32,
                       const int* __restrict__ perm,
                       const float* __restrict__ out_idx,
                       float* __restrict__ es)
{
    __shared__ int sperm[32];
    __shared__ int scode[32];
    const int base = blockIdx.x * 32;
    const int tid = threadIdx.x;
    const int j = tid & 127;
    const uint32_t* __restrict__ A = (tid >> 7) ? A_lo32 : A_hi32;
    if (tid < 32) {
        int t = perm[base + tid];
        sperm[tid] = t;
        scode[tid] = (int)out_idx[t];
    }
    __syncthreads();

    float s0 = 0.f, s1 = 0.f;
    int cur = scode[0];
    uint32_t pu[2];
    pu[0] = A[sperm[0] * 128 + j];
    pu[1] = A[sperm[1] * 128 + j];
#pragma unroll
    for (int i = 0; i < 32; ++i) {
        uint32_t u = pu[i & 1];
        if (i + 2 < 32) pu[i & 1] = A[sperm[i + 2] * 128 + j];
        int code = scode[i];
        if (code != cur) {
            atomicAdd(&es[cur * 256 + 2 * j],     s0);
            atomicAdd(&es[cur * 256 + 2 * j + 1], s1);
            s0 = 0.f; s1 = 0.f; cur = code;
        }
        s0 += (float)__builtin_bit_cast(_Float16, (unsigned short)(u & 0xffffu));
        s1 += (float)__builtin_bit_cast(_Float16, (unsigned short)(u >> 16));
    }
    atomicAdd(&es[cur * 256 + 2 * j],     s0);
    atomicAdd(&es[cur * 256 + 2 * j + 1], s1);
}

// ---- EMA finalize for embed_avg / embed (overwrites best64 scratch) ----
__global__ void finalize_embed(const float* __restrict__ embed_avg,
                               const float* __restrict__ es,
                               const float* __restrict__ csnorm,
                               float* __restrict__ out_embed,
                               float* __restrict__ out_nea)
{
    int idx = blockIdx.x * 256 + threadIdx.x;
    int k = idx >> 8;
    float nea = embed_avg[idx] * DECAY + OMDECAY * es[idx];
    out_nea[idx] = nea;
    out_embed[idx] = nea / csnorm[k];
}

extern "C" void kernel_launch(void* const* d_in, const int* in_sizes, int n_in,
                              void* d_out, int out_size, void* d_ws, size_t ws_size,
                              hipStream_t stream) {
    const float* z            = (const float*)d_in[0];
    const float* embed        = (const float*)d_in[1];
    const float* cluster_size = (const float*)d_in[2];
    const float* embed_avg    = (const float*)d_in[3];
    float* out = (float*)d_out;
    uint32_t* ws32 = (uint32_t*)d_ws;

    uint32_t* B_hi32 = ws32 + 0;
    uint32_t* B_lo32 = ws32 + 131072;
    uint32_t* A_hi32 = ws32 + 262144;
    uint32_t* A_lo32 = ws32 + 4456448;
    int* perm        = (int*)(ws32 + 8650752);
    int* offsets     = (int*)(ws32 + 8683520);
    int* cursor      = (int*)(ws32 + 8684544);
    float* cs        = (float*)(ws32 + 8912896);
    float* loss_sum  = (float*)(ws32 + 8913920);
    float* enorm     = (float*)(ws32 + 8914944);
    float* csnorm    = (float*)(ws32 + 8915968);
    float* es        = (float*)(ws32 + 0);        // reuses B_hi/B_lo after vq_mfma
    // best64 scratch overlays the new_embed output region (8-byte aligned)
    unsigned long long* best64 = (unsigned long long*)(out + 8421378);

    prep_embed<<<1024, 256, 0, stream>>>(embed, (unsigned short*)B_hi32,
                                         (unsigned short*)B_lo32, enorm, cs,
                                         (uint32_t*)best64);
    split_z<<<1024, 256, 0, stream>>>(z, A_hi32, A_lo32);
    vq_mfma<<<512, 256, 0, stream>>>(A_hi32, A_lo32, B_hi32, B_lo32, enorm, best64);
    merge_zq<<<256, 256, 0, stream>>>(best64, z, embed,
                                      out, out + 8388608, cs, loss_sum);
    vq_finalize_small<<<1, 1024, 0, stream>>>(cluster_size, cs, loss_sum,
                                              out + 8421376, out + 8683521, csnorm,
                                              offsets, cursor);
    scatter_perm<<<128, 256, 0, stream>>>(out + 8388608, cursor, perm, es);
    es_sum<<<1024, 256, 0, stream>>>(A_hi32, A_lo32, perm, out + 8388608, es);
    finalize_embed<<<1024, 256, 0, stream>>>(embed_avg, es, csnorm,
                                             out + 8421377, out + 8684545);
}